// Round 6
// baseline (19.462 us; speedup 1.0000x reference)
//
#include <hip/hip_runtime.h>

// MLS rigid deformation, fused single-pass complex form, minimal-slot scalar loop.
//
// Per pixel v: w_n = 1/(|p_n - v|^2 + 1e-9)
//   pstar = (sum w p)/sw, qstar = (sum w q)/sw, vp = v - pstar
//   S = sum_n w_n q_n conj(p_n) - (sum w q) conj(sum w p)/sw
//   frv = vp * S;  out = |vp| * frv/|frv| + qstar
//
// frv/|frv| is invariant under positive scaling of S, so use
//   S' = sw*(sre,sim) - swq*conj(swp)        (no rsw in the correction)
//
// Per-point constants cre=Re(q conj p), cim=Im(q conj p): lane n computes
// point n's pair once; the unrolled loop broadcasts via v_readlane (2 slots
// per point, shared by both pixels). px,py,qx,qy come from the scalar pipe
// (s_load at uniform addresses). Inner loop: 12 full-rate scalar VALU slots
// + 1 v_rcp per pixel-point. No LDS, no pk ops (half-rate on gfx950).

#define IMG_H 768
#define IMG_W 768
#define NPTS 64

__device__ __forceinline__ float rdlane(float v, int lane) {
    return __int_as_float(__builtin_amdgcn_readlane(__float_as_int(v), lane));
}

__device__ __forceinline__ float2 mls_finish(
    float vxk, float vy, float sw,
    float spx, float spy, float sqx, float sqy,
    float sre, float sim)
{
    const float rsw = __builtin_amdgcn_rcpf(sw);
    const float psx = spx * rsw, psy = spy * rsw;     // pstar
    const float qsx = sqx * rsw, qsy = sqy * rsw;     // qstar
    // S' = sw*(sre,sim) - swq*conj(swp)   (positive multiple of S)
    const float Sre = fmaf(sw, sre, -fmaf(sqx, spx,  sqy * spy));
    const float Sim = fmaf(sw, sim, -fmaf(sqy, spx, -sqx * spy));
    const float vpx = vxk - psx;
    const float vpy = vy - psy;
    const float frx = fmaf(vpx, Sre, -vpy * Sim);
    const float fry = fmaf(vpx, Sim, vpy * Sre);
    const float vpn = sqrtf(fmaf(vpx, vpx, vpy * vpy));
    const float frn = sqrtf(fmaf(frx, frx, fry * fry)) + 1e-10f;
    const float s = vpn * __builtin_amdgcn_rcpf(frn);
    return make_float2(fmaf(s, frx, qsx), fmaf(s, fry, qsy));
}

__global__ __launch_bounds__(256) void mls_main(
    const float* __restrict__ pi,
    const float* __restrict__ qi,
    float* __restrict__ out)
{
    const int tid = threadIdx.x;
    const int lane = tid & 63;

    // Lane n computes point n's complex product q*conj(p) once.
    const float2 lp = ((const float2*)pi)[lane];
    const float2 lq = ((const float2*)qi)[lane];
    const float lcre = fmaf(lq.x, lp.x,  lq.y * lp.y);
    const float lcim = fmaf(lq.y, lp.x, -lq.x * lp.y);

    const int idx = blockIdx.x * 256 + tid;           // one thread = 2 pixels
    const int xh = idx % (IMG_W / 2);
    const int y  = idx / (IMG_W / 2);
    const float vx = (float)(2 * xh);
    const float vy = (float)y;

    float sw0 = 0.f, spx0 = 0.f, spy0 = 0.f, sqx0 = 0.f, sqy0 = 0.f, sre0 = 0.f, sim0 = 0.f;
    float sw1 = 0.f, spx1 = 0.f, spy1 = 0.f, sqx1 = 0.f, sqy1 = 0.f, sre1 = 0.f, sim1 = 0.f;

    #pragma unroll
    for (int n = 0; n < NPTS; ++n) {
        // Uniform addresses -> scalar pipe (s_load), zero VALU slots.
        const float px = pi[2 * n + 0];
        const float py = pi[2 * n + 1];
        const float qx = qi[2 * n + 0];
        const float qy = qi[2 * n + 1];
        // Broadcast per-point constants from lane n (2 VALU slots, shared by 2 px).
        const float cre = rdlane(lcre, n);
        const float cim = rdlane(lcim, n);

        const float dx = px - vx;
        const float dy = py - vy;
        const float t  = fmaf(dy, dy, 1e-9f);
        const float d0 = fmaf(dx, dx, t);
        const float d1 = fmaf(-2.f, dx, d0) + 1.0f;   // |p - (vx+1,vy)|^2
        const float w0 = __builtin_amdgcn_rcpf(d0);
        const float w1 = __builtin_amdgcn_rcpf(d1);

        sw0  += w0;                   sw1  += w1;
        spx0 = fmaf(w0, px,  spx0);   spx1 = fmaf(w1, px,  spx1);
        spy0 = fmaf(w0, py,  spy0);   spy1 = fmaf(w1, py,  spy1);
        sqx0 = fmaf(w0, qx,  sqx0);   sqx1 = fmaf(w1, qx,  sqx1);
        sqy0 = fmaf(w0, qy,  sqy0);   sqy1 = fmaf(w1, qy,  sqy1);
        sre0 = fmaf(w0, cre, sre0);   sre1 = fmaf(w1, cre, sre1);
        sim0 = fmaf(w0, cim, sim0);   sim1 = fmaf(w1, cim, sim1);
    }

    const float2 r0 = mls_finish(vx,       vy, sw0, spx0, spy0, sqx0, sqy0, sre0, sim0);
    const float2 r1 = mls_finish(vx + 1.f, vy, sw1, spx1, spy1, sqx1, sqy1, sre1, sim1);

    ((float4*)out)[idx] = make_float4(r0.x, r0.y, r1.x, r1.y);
}

extern "C" void kernel_launch(void* const* d_in, const int* in_sizes, int n_in,
                              void* d_out, int out_size, void* d_ws, size_t ws_size,
                              hipStream_t stream) {
    // d_in[0] = img (unused), d_in[1] = pi (64,2) f32, d_in[2] = qi (64,2) f32
    const float* pi = (const float*)d_in[1];
    const float* qi = (const float*)d_in[2];
    float* out = (float*)d_out;

    const int nthreads = IMG_H * (IMG_W / 2);         // 294912
    mls_main<<<nthreads / 256, 256, 0, stream>>>(pi, qi, out);   // 1152 blocks
}